// Round 9
// baseline (390.467 us; speedup 1.0000x reference)
//
#include <hip/hip_runtime.h>

// ---------- types ----------
typedef __bf16 vbf8 __attribute__((ext_vector_type(8)));
typedef unsigned short us8 __attribute__((ext_vector_type(8)));
typedef float f32x4 __attribute__((ext_vector_type(4)));
typedef float f32x4u __attribute__((ext_vector_type(4), aligned(4)));

#define NBLK 64

// ---------- band-case helpers ----------
__device__ __forceinline__ int caseof(int h, int H, int e) {
  if (h < 0 || h >= H) return -1;           // EDGE
  if (h < e) return h;
  if (h >= H - e) return h - (H - 1) + 2 * e;
  return e;
}
__device__ __forceinline__ int repof(int i, int H, int eo) {
  return (i <= eo) ? i : H - 1 - 2 * eo + i;
}

__device__ __forceinline__ vbf8 max8(vbf8 a, vbf8 b) {
  us8 ua = __builtin_bit_cast(us8, a), ub = __builtin_bit_cast(us8, b);
  us8 o;
#pragma unroll
  for (int e = 0; e < 8; ++e) o[e] = ua[e] > ub[e] ? ua[e] : ub[e];
  return __builtin_bit_cast(vbf8, o);
}

// ---------- device-scope grid barrier v3 ----------
// ALL barrier traffic via atomic RMWs (coherent-point guaranteed; a relaxed
// atomic LOAD may be served stale from the local non-coherent L2).
// One acquire-only fence by every block (winner included) after release.
__device__ __forceinline__ void gridbar(int* bar) {
  __syncthreads();
  if (threadIdx.x == 0) {
    int* cnt = bar; int* gen = bar + 1;
    int g = __hip_atomic_fetch_add(gen, 0, __ATOMIC_RELAXED, __HIP_MEMORY_SCOPE_AGENT);
    if (__hip_atomic_fetch_add(cnt, 1, __ATOMIC_ACQ_REL, __HIP_MEMORY_SCOPE_AGENT) == NBLK - 1) {
      __hip_atomic_fetch_add(cnt, -NBLK, __ATOMIC_RELAXED, __HIP_MEMORY_SCOPE_AGENT);
      __hip_atomic_fetch_add(gen, 1, __ATOMIC_RELEASE, __HIP_MEMORY_SCOPE_AGENT);
    } else {
      while (__hip_atomic_fetch_add(gen, 0, __ATOMIC_RELAXED, __HIP_MEMORY_SCOPE_AGENT) == g)
        __builtin_amdgcn_s_sleep(32);
    }
  }
  __syncthreads();
  __builtin_amdgcn_fence(__ATOMIC_ACQUIRE, "agent");
}

// ---------------------------------------------------------------------------
// setup: precompute MFMA weight fragments for the pillar net.
// ---------------------------------------------------------------------------
__global__ void setup_kernel(const float* __restrict__ w1, const float* __restrict__ b1,
                             const float* __restrict__ s1, const float* __restrict__ t1,
                             const float* __restrict__ w2, const float* __restrict__ b2,
                             const float* __restrict__ s2, const float* __restrict__ t2,
                             __bf16* __restrict__ wfrag, float* __restrict__ be2f) {
  int l = threadIdx.x;                       // 0..63
  int s = l & 15, g = l >> 4;
#pragma unroll
  for (int m = 0; m < 4; ++m) {
    int c = 32 * (m & 1) + 8 * (s >> 2) + 4 * (m >> 1) + (s & 3);
#pragma unroll
    for (int e = 0; e < 8; ++e) {
      int k = g * 8 + e;
      float v = 0.f;
      if (k < 9)       v = w1[k * 64 + c] * s1[c];
      else if (k == 9) v = fmaf(b1[c], s1[c], t1[c]);
      wfrag[(m * 64 + l) * 8 + e] = (__bf16)v;
    }
    int co = s + 16 * m;
#pragma unroll
    for (int e = 0; e < 8; ++e) {
      int k = g * 8 + e;
      wfrag[((4 + m) * 64 + l) * 8 + e] = (__bf16)(w2[k * 64 + co] * s2[co]);
      wfrag[((8 + m) * 64 + l) * 8 + e] = (__bf16)(w2[(32 + k) * 64 + co] * s2[co]);
    }
    be2f[m * 64 + l] = fmaf(b2[co], s2[co], t2[co]);
  }
}

// ---------------------------------------------------------------------------
// weight transpose+convert, LDS-tiled: HWIO [tap][ci][co] f32 -> [tap][co][ci] bf16
// ---------------------------------------------------------------------------
__global__ __launch_bounds__(256) void convw_kernel(
    const float* __restrict__ k1, const float* __restrict__ k2,
    const float* __restrict__ k3, const float* __restrict__ k4,
    const float* __restrict__ k5, const float* __restrict__ k6,
    const float* __restrict__ kh, __bf16* __restrict__ wT) {
  __shared__ float tile[64][65];
  const int tCI[7]    = {64, 64, 64, 128, 128, 256, 256};
  const int tCO[7]    = {64, 64, 128, 128, 256, 256, 256};
  const int tOFF[7]   = {0, 36864, 73728, 147456, 294912, 589824, 1179648};
  const int tTILES[7] = {9, 9, 18, 36, 72, 144, 144};
  int bid = blockIdx.x;
  int ti = 0, acc = 0;
  while (ti < 6 && bid >= acc + tTILES[ti]) { acc += tTILES[ti]; ++ti; }
  int lt = bid - acc;
  int CI = tCI[ti], CO = tCO[ti];
  const float* src;
  if (ti == 0) src = k1; else if (ti == 1) src = k2; else if (ti == 2) src = k3;
  else if (ti == 3) src = k4; else if (ti == 4) src = k5; else if (ti == 5) src = k6;
  else src = kh;
  int cot = CO / 64, tpt = (CI / 64) * cot;
  int tap = lt / tpt; int r2 = lt - tap * tpt;
  int ci0 = (r2 / cot) * 64, co0 = (r2 % cot) * 64;
  const float* sp = src + (size_t)(tap * CI + ci0) * CO + co0;
  int t = threadIdx.x;
  int lr = t >> 6, lc = t & 63;
#pragma unroll
  for (int rr = 0; rr < 64; rr += 4)
    tile[rr + lr][lc] = sp[(size_t)(rr + lr) * CO + lc];
  __syncthreads();
  __bf16* dst = wT + tOFF[ti] + ((size_t)tap * CO + co0) * CI + ci0;
#pragma unroll
  for (int rr = 0; rr < 64; rr += 4)
    dst[(size_t)(rr + lr) * CI + lc] = (__bf16)tile[lc][rr + lr];
}

// ---------------------------------------------------------------------------
// Stage A: pillar feature net, 1-deep group software pipeline (unchanged R8).
// ---------------------------------------------------------------------------
__global__ __launch_bounds__(256) void pillar_kernel(
    const float* __restrict__ pil, const int* __restrict__ npt,
    const __bf16* __restrict__ wfrag, const float* __restrict__ be2f,
    float* __restrict__ partial, int* __restrict__ pcnt)
{
  __shared__ float redf[4][64];
  __shared__ int redc[4];
  const int tid = threadIdx.x;
  const int wv = tid >> 6, lane = tid & 63;
  const int s = lane & 15, g = lane >> 4;
  const int wid = blockIdx.x * 4 + wv;       // 0..23999
  const int b = wid / 6000;
  const int p0 = (wid - b * 6000) * 2;

  vbf8 w1f[4], w2f0[4], w2f1[4];
  float be2[4];
#pragma unroll
  for (int m = 0; m < 4; ++m) {
    w1f[m]  = *(const vbf8*)(wfrag + ((0 + m) * 64 + lane) * 8);
    w2f0[m] = *(const vbf8*)(wfrag + ((4 + m) * 64 + lane) * 8);
    w2f1[m] = *(const vbf8*)(wfrag + ((8 + m) * 64 + lane) * 8);
    be2[m] = be2f[m * 64 + lane];
  }

  float fsum[4] = {0.f, 0.f, 0.f, 0.f};
  int cnt = 0;

  for (int i = 0; i < 2; ++i) {
    int pidx = b * 12000 + p0 + i;
    int np = npt[pidx];
    if (np <= 0) continue;     // wave-uniform
    ++cnt;
    float feat[4][4];
#pragma unroll
    for (int n = 0; n < 4; ++n)
#pragma unroll
      for (int r = 0; r < 4; ++r) feat[n][r] = 0.f;

    int ngrp = (np + 15) >> 4;
    const float* pbase = pil + (size_t)pidx * 900;
    const float* pp0 = pbase + s * 9;
    f32x4u lo = *(const f32x4u*)pp0;
    f32x4u hi = *(const f32x4u*)(pp0 + 4);
    float v8 = pp0[8];
    for (int grp = 0; grp < ngrp; ++grp) {
      int g2 = min(grp + 1, ngrp - 1);
      int ptn = min(g2 * 16 + s, 99);
      const float* ppn = pbase + ptn * 9;
      f32x4u nlo = *(const f32x4u*)ppn;
      f32x4u nhi = *(const f32x4u*)(ppn + 4);
      float nv8 = ppn[8];

      vbf8 b1f;
      b1f[0] = (__bf16)(g == 0 ? lo[0] : (g == 1 ? v8 : 0.f));
      b1f[1] = (__bf16)(g == 0 ? lo[1] : (g == 1 ? 1.0f : 0.f));
      b1f[2] = (__bf16)(g == 0 ? lo[2] : 0.f);
      b1f[3] = (__bf16)(g == 0 ? lo[3] : 0.f);
      b1f[4] = (__bf16)(g == 0 ? hi[0] : 0.f);
      b1f[5] = (__bf16)(g == 0 ? hi[1] : 0.f);
      b1f[6] = (__bf16)(g == 0 ? hi[2] : 0.f);
      b1f[7] = (__bf16)(g == 0 ? hi[3] : 0.f);

      const f32x4 z = {0.f, 0.f, 0.f, 0.f};
      f32x4 d1[4];
#pragma unroll
      for (int m = 0; m < 4; ++m)
        d1[m] = __builtin_amdgcn_mfma_f32_16x16x32_bf16(w1f[m], b1f, z, 0, 0, 0);

      vbf8 a2f0, a2f1;
#pragma unroll
      for (int r = 0; r < 4; ++r) {
        a2f0[r]     = (__bf16)fmaxf(d1[0][r], 0.f);
        a2f1[r]     = (__bf16)fmaxf(d1[1][r], 0.f);
        a2f0[4 + r] = (__bf16)fmaxf(d1[2][r], 0.f);
        a2f1[4 + r] = (__bf16)fmaxf(d1[3][r], 0.f);
      }

      f32x4 d2[4];
#pragma unroll
      for (int n = 0; n < 4; ++n) {
        f32x4 cb = {be2[n], be2[n], be2[n], be2[n]};
        d2[n] = __builtin_amdgcn_mfma_f32_16x16x32_bf16(a2f0, w2f0[n], cb, 0, 0, 0);
        d2[n] = __builtin_amdgcn_mfma_f32_16x16x32_bf16(a2f1, w2f1[n], d2[n], 0, 0, 0);
      }
      if (((grp + 1) << 4) <= np) {
#pragma unroll
        for (int n = 0; n < 4; ++n)
#pragma unroll
          for (int r = 0; r < 4; ++r) feat[n][r] = fmaxf(feat[n][r], d2[n][r]);
      } else {
#pragma unroll
        for (int n = 0; n < 4; ++n)
#pragma unroll
          for (int r = 0; r < 4; ++r) {
            float vv = (grp * 16 + 4 * g + r < np) ? d2[n][r] : 0.f;
            feat[n][r] = fmaxf(feat[n][r], vv);
          }
      }
      lo = nlo; hi = nhi; v8 = nv8;
    }
#pragma unroll
    for (int n = 0; n < 4; ++n) {
      float m = fmaxf(fmaxf(feat[n][0], feat[n][1]), fmaxf(feat[n][2], feat[n][3]));
      m = fmaxf(m, __shfl_xor(m, 16));
      m = fmaxf(m, __shfl_xor(m, 32));
      fsum[n] += m;
    }
  }
  if (g == 0) {
#pragma unroll
    for (int n = 0; n < 4; ++n) redf[wv][s + 16 * n] = fsum[n];
  }
  if (lane == 0) redc[wv] = cnt;
  __syncthreads();
  if (tid < 64) {
    float tot = redf[0][tid] + redf[1][tid] + redf[2][tid] + redf[3][tid];
    partial[blockIdx.x * 64 + tid] = tot;
    if (tid == 0) pcnt[blockIdx.x] = redc[0] + redc[1] + redc[2] + redc[3];
  }
}

// finish mean + emit X0 + zero zbuf page + zero grid barrier state
__global__ void mean_kernel(const float* __restrict__ partial,
                            const int* __restrict__ pcnt,
                            __bf16* __restrict__ x0,
                            __bf16* __restrict__ zbuf, int* __restrict__ bar) {
  int b = blockIdx.x, t = threadIdx.x;
  if (b == 0) {
    zbuf[t] = (__bf16)0.f;
    if (t < 2) bar[t] = 0;
  }
  int c = t & 63, q = t >> 6;
  float sum = 0.f;
  for (int w = q; w < 1500; w += 4) sum += partial[(b * 1500 + w) * 64 + c];
  int cl = 0;
  for (int w = t; w < 1500; w += 256) cl += pcnt[b * 1500 + w];
  __shared__ float sh[256];
  __shared__ int shc[256];
  sh[t] = sum; shc[t] = cl;
  __syncthreads();
  for (int o = 128; o > 0; o >>= 1) {
    if (t < o) shc[t] += shc[t + o];
    __syncthreads();
  }
  if (t < 64) {
    float tot = sh[t] + sh[t + 64] + sh[t + 128] + sh[t + 192];
    x0[b * 64 + t] = (__bf16)(tot / (float)(shc[0] > 0 ? shc[0] : 1));
  }
}

// ---------------------------------------------------------------------------
// Case-grid conv device fn. If POOL: input is the pre-pool grid at size 2H
// with band EIN; 2x2 max pooling fused into the A-fragment loads.
// ---------------------------------------------------------------------------
template <int CI, int CO, int H, int EIN, bool POOL, bool HAS_BN, bool OUT_F32>
__device__ __forceinline__ void caseconv_dev(
    int wid, const __bf16* __restrict__ xin, const __bf16* __restrict__ wt,
    const float* __restrict__ cb, const float* __restrict__ cs,
    const float* __restrict__ ct, __bf16* __restrict__ yout,
    float* __restrict__ yf32, const __bf16* __restrict__ zbuf)
{
  constexpr int EV   = POOL ? (EIN + 1) / 2 : EIN;   // virtual input band @ H
  constexpr int EOUT = EV + 1;
  constexpr int NBI  = 2 * EIN + 1;                  // physical input grid dim
  constexpr int HX   = POOL ? 2 * H : H;             // physical input size
  constexpr int NBO  = 2 * EOUT + 1;
  constexpr int M    = NBO * NBO * 4;
  constexpr int NT   = CO / 16;
  constexpr int KC   = CI / 32;
  constexpr int MT   = (M + 31) / 32;
  if (wid >= MT * NT) return;
  const int lane = threadIdx.x & 63;
  const int s = lane & 15, g = lane >> 4;
  const int nt = wid % NT, mt = wid / NT;

  int reph[2], repw[2], bsel[2];
#pragma unroll
  for (int mf = 0; mf < 2; ++mf) {
    int m = mt * 32 + mf * 16 + s; if (m >= M) m = M - 1;
    bsel[mf] = m & 3; int q = m >> 2;
    int bw = q % NBO, bh = q / NBO;
    reph[mf] = repof(bh, H, EOUT); repw[mf] = repof(bw, H, EOUT);
  }

  f32x4 acc0 = {0.f, 0.f, 0.f, 0.f}, acc1 = {0.f, 0.f, 0.f, 0.f};
#pragma unroll
  for (int tap = 0; tap < 9; ++tap) {
    const int dh = tap / 3, dw = tap % 3;
    const __bf16* wtap = wt + ((size_t)tap * CO + nt * 16) * CI + 8 * g;
    const __bf16* base[2][POOL ? 4 : 1];
#pragma unroll
    for (int mf = 0; mf < 2; ++mf) {
      int vh = reph[mf] + dh - 1, vw = repw[mf] + dw - 1;
      if constexpr (POOL) {
        bool valid = (vh >= 0) && (vh < H) && (vw >= 0) && (vw < H);
        int h0 = 0, h1 = 0, w0 = 0, w1 = 0;
        if (valid) {
          h0 = caseof(2 * vh, HX, EIN); h1 = caseof(2 * vh + 1, HX, EIN);
          w0 = caseof(2 * vw, HX, EIN); w1 = caseof(2 * vw + 1, HX, EIN);
        }
        base[mf][0] = valid ? xin + (size_t)((h0 * NBI + w0) * 4 + bsel[mf]) * CI : zbuf;
        base[mf][1] = valid ? xin + (size_t)((h0 * NBI + w1) * 4 + bsel[mf]) * CI : zbuf;
        base[mf][2] = valid ? xin + (size_t)((h1 * NBI + w0) * 4 + bsel[mf]) * CI : zbuf;
        base[mf][3] = valid ? xin + (size_t)((h1 * NBI + w1) * 4 + bsel[mf]) * CI : zbuf;
      } else {
        int jh = caseof(vh, H, EIN), jw = caseof(vw, H, EIN);
        bool v = (jh >= 0) && (jw >= 0);
        base[mf][0] = v ? xin + (size_t)((jh * NBI + jw) * 4 + bsel[mf]) * CI : zbuf;
      }
    }
#pragma unroll
    for (int ck = 0; ck < KC; ++ck) {
      vbf8 a0, a1;
      if constexpr (POOL) {
        a0 = max8(max8(*(const vbf8*)(base[0][0] + ck * 32 + 8 * g),
                       *(const vbf8*)(base[0][1] + ck * 32 + 8 * g)),
                  max8(*(const vbf8*)(base[0][2] + ck * 32 + 8 * g),
                       *(const vbf8*)(base[0][3] + ck * 32 + 8 * g)));
        a1 = max8(max8(*(const vbf8*)(base[1][0] + ck * 32 + 8 * g),
                       *(const vbf8*)(base[1][1] + ck * 32 + 8 * g)),
                  max8(*(const vbf8*)(base[1][2] + ck * 32 + 8 * g),
                       *(const vbf8*)(base[1][3] + ck * 32 + 8 * g)));
      } else {
        a0 = *(const vbf8*)(base[0][0] + ck * 32 + 8 * g);
        a1 = *(const vbf8*)(base[1][0] + ck * 32 + 8 * g);
      }
      vbf8 bb = *(const vbf8*)(wtap + (size_t)s * CI + ck * 32);
      acc0 = __builtin_amdgcn_mfma_f32_16x16x32_bf16(a0, bb, acc0, 0, 0, 0);
      acc1 = __builtin_amdgcn_mfma_f32_16x16x32_bf16(a1, bb, acc1, 0, 0, 0);
    }
  }

  int co = nt * 16 + s;
  float sc, sh;
  if (HAS_BN) { sc = cs[co]; sh = fmaf(cb[co], sc, ct[co]); }
  else        { sc = 1.f;    sh = cb[co]; }
#pragma unroll
  for (int mf = 0; mf < 2; ++mf) {
    f32x4 acc = mf ? acc1 : acc0;
#pragma unroll
    for (int r = 0; r < 4; ++r) {
      int m = mt * 32 + mf * 16 + 4 * g + r;
      if (m < M) {
        float v = fmaxf(fmaf(acc[r], sc, sh), 0.f);
        if constexpr (OUT_F32) yf32[(size_t)m * CO + co] = v;
        else                   yout[(size_t)m * CO + co] = (__bf16)v;
      }
    }
  }
}

// fused 1x1 head conv + scatter: each output element computes its own 256-dot
__device__ __forceinline__ void headscatter_dev(int gtid, const float* __restrict__ x,
                                                const float* __restrict__ wk,
                                                const float* __restrict__ bias,
                                                float* __restrict__ out) {
  for (int idx = gtid; idx < 4 * 10 * 27 * 31; idx += NBLK * 256) {
    int c = idx % 31;
    int r = (idx / 31) % 27;
    int ch = (idx / (31 * 27)) % 10;
    int b = idx / (31 * 27 * 10);
    int rr = (r <= 7) ? r : ((r >= 20) ? r - 11 : 7);
    int cc = (c <= 7) ? c : ((c >= 24) ? c - 15 : 7);
    int ph = caseof(rr, 16, 5), pw = caseof(cc, 16, 5);
    const float* xr = x + (size_t)((ph * 11 + pw) * 4 + b) * 256;
    float a0 = 0.f, a1 = 0.f, a2 = 0.f, a3 = 0.f;
#pragma unroll 4
    for (int ci = 0; ci < 256; ci += 4) {
      float4 in4 = *(const float4*)(xr + ci);
      a0 = fmaf(in4.x, wk[(ci + 0) * 10 + ch], a0);
      a1 = fmaf(in4.y, wk[(ci + 1) * 10 + ch], a1);
      a2 = fmaf(in4.z, wk[(ci + 2) * 10 + ch], a2);
      a3 = fmaf(in4.w, wk[(ci + 3) * 10 + ch], a3);
    }
    out[idx] = (a0 + a1) + (a2 + a3) + bias[ch];
  }
}

// ---------------------------------------------------------------------------
// fused backbone: 7 convs (2 with fused pool) + head+scatter, 7 grid barriers
// ---------------------------------------------------------------------------
__global__ __launch_bounds__(256) void backbone_kernel(
    const __bf16* __restrict__ X0, __bf16* __restrict__ X1, __bf16* __restrict__ X2,
    __bf16* __restrict__ X3, __bf16* __restrict__ X4, __bf16* __restrict__ X5,
    __bf16* __restrict__ X6, float* __restrict__ XH,
    const __bf16* wt1, const __bf16* wt2, const __bf16* wt3, const __bf16* wt4,
    const __bf16* wt5, const __bf16* wt6, const __bf16* wth,
    const float* cb1, const float* cs1, const float* ct1,
    const float* cb2, const float* cs2, const float* ct2,
    const float* cb3, const float* cs3, const float* ct3,
    const float* cb4, const float* cs4, const float* ct4,
    const float* cb5, const float* cs5, const float* ct5,
    const float* cb6, const float* cs6, const float* ct6,
    const float* hb1, const float* hk2, const float* hb2,
    const __bf16* __restrict__ zbuf, int* __restrict__ bar, float* __restrict__ out)
{
  const int wid = blockIdx.x * 4 + (threadIdx.x >> 6);
  const int gtid = blockIdx.x * 256 + threadIdx.x;

  caseconv_dev<64, 64, 64, 0, false, true, false>(wid, X0, wt1, cb1, cs1, ct1, X1, nullptr, zbuf);
  gridbar(bar);
  caseconv_dev<64, 64, 64, 1, false, true, false>(wid, X1, wt2, cb2, cs2, ct2, X2, nullptr, zbuf);
  gridbar(bar);
  caseconv_dev<64, 128, 32, 2, true, true, false>(wid, X2, wt3, cb3, cs3, ct3, X3, nullptr, zbuf);
  gridbar(bar);
  caseconv_dev<128, 128, 32, 2, false, true, false>(wid, X3, wt4, cb4, cs4, ct4, X4, nullptr, zbuf);
  gridbar(bar);
  caseconv_dev<128, 256, 16, 3, true, true, false>(wid, X4, wt5, cb5, cs5, ct5, X5, nullptr, zbuf);
  gridbar(bar);
  caseconv_dev<256, 256, 16, 3, false, true, false>(wid, X5, wt6, cb6, cs6, ct6, X6, nullptr, zbuf);
  gridbar(bar);
  caseconv_dev<256, 256, 16, 4, false, false, true>(wid, X6, wth, hb1, nullptr, nullptr, nullptr, XH, zbuf);
  gridbar(bar);
  headscatter_dev(gtid, XH, hk2, hb2, out);
}

// ---------------------------------------------------------------------------
extern "C" void kernel_launch(void* const* d_in, const int* in_sizes, int n_in,
                              void* d_out, int out_size, void* d_ws, size_t ws_size,
                              hipStream_t stream) {
  (void)in_sizes; (void)n_in; (void)out_size; (void)ws_size;
  const float* pillars = (const float*)d_in[0];
  const float* w1 = (const float*)d_in[1];
  const float* b1 = (const float*)d_in[2];
  const float* s1 = (const float*)d_in[3];
  const float* t1 = (const float*)d_in[4];
  const float* w2 = (const float*)d_in[5];
  const float* b2 = (const float*)d_in[6];
  const float* s2 = (const float*)d_in[7];
  const float* t2 = (const float*)d_in[8];
  const float* ck[6], *cbv[6], *csv[6], *ctv[6];
  for (int i = 0; i < 6; ++i) {
    ck[i]  = (const float*)d_in[9 + i * 4];
    cbv[i] = (const float*)d_in[10 + i * 4];
    csv[i] = (const float*)d_in[11 + i * 4];
    ctv[i] = (const float*)d_in[12 + i * 4];
  }
  const float* hk1 = (const float*)d_in[33];
  const float* hb1 = (const float*)d_in[34];
  const float* hk2 = (const float*)d_in[35];
  const float* hb2 = (const float*)d_in[36];
  const int* num_points = (const int*)d_in[37];
  float* out = (float*)d_out;

  // ---- ws layout ----
  char* wsb = (char*)d_ws;
  size_t off = 0;
  auto alloc = [&](size_t n) { char* p = wsb + off; off = (off + n + 255) & ~(size_t)255; return p; };
  float*  ppart = (float*)alloc(1536000);
  int*    pcnt  = (int*)alloc(24000);
  __bf16* wfrag = (__bf16*)alloc(12288);
  float*  be2f  = (float*)alloc(1024);
  __bf16* wT    = (__bf16*)alloc(3538944);
  __bf16* zbuf  = (__bf16*)alloc(512);
  int*    bar   = (int*)alloc(256);
  __bf16* X0    = (__bf16*)alloc(512);       // 1x1x4x64
  __bf16* X1    = (__bf16*)alloc(4608);      // 3x3x4x64
  __bf16* X2    = (__bf16*)alloc(12800);     // 5x5x4x64
  __bf16* X3    = (__bf16*)alloc(25600);     // 5x5x4x128
  __bf16* X4    = (__bf16*)alloc(50176);     // 7x7x4x128
  __bf16* X5    = (__bf16*)alloc(100352);    // 7x7x4x256
  __bf16* X6    = (__bf16*)alloc(165888);    // 9x9x4x256
  float*  XH    = (float*)alloc(495616);     // 11x11x4x256 f32

  __bf16* wt1 = wT + 0;       __bf16* wt2 = wT + 36864;
  __bf16* wt3 = wT + 73728;   __bf16* wt4 = wT + 147456;
  __bf16* wt5 = wT + 294912;  __bf16* wt6 = wT + 589824;
  __bf16* wth = wT + 1179648;

  setup_kernel<<<1, 64, 0, stream>>>(w1, b1, s1, t1, w2, b2, s2, t2, wfrag, be2f);
  convw_kernel<<<432, 256, 0, stream>>>(ck[0], ck[1], ck[2], ck[3], ck[4], ck[5],
                                        hk1, wT);
  pillar_kernel<<<6000, 256, 0, stream>>>(pillars, num_points, wfrag, be2f,
                                          ppart, pcnt);
  mean_kernel<<<4, 256, 0, stream>>>(ppart, pcnt, X0, zbuf, bar);
  backbone_kernel<<<NBLK, 256, 0, stream>>>(
      X0, X1, X2, X3, X4, X5, X6, XH,
      wt1, wt2, wt3, wt4, wt5, wt6, wth,
      cbv[0], csv[0], ctv[0], cbv[1], csv[1], ctv[1],
      cbv[2], csv[2], ctv[2], cbv[3], csv[3], ctv[3],
      cbv[4], csv[4], ctv[4], cbv[5], csv[5], ctv[5],
      hb1, hk2, hb2, zbuf, bar, out);
}

// Round 10
// 363.304 us; speedup vs baseline: 1.0748x; 1.0748x over previous
//
#include <hip/hip_runtime.h>

// ---------- types ----------
typedef __bf16 vbf8 __attribute__((ext_vector_type(8)));
typedef unsigned short us8 __attribute__((ext_vector_type(8)));
typedef float f32x4 __attribute__((ext_vector_type(4)));
typedef float f32x4u __attribute__((ext_vector_type(4), aligned(4)));

// ---------- band-case helpers ----------
__device__ __forceinline__ int caseof(int h, int H, int e) {
  if (h < 0 || h >= H) return -1;           // EDGE
  if (h < e) return h;
  if (h >= H - e) return h - (H - 1) + 2 * e;
  return e;
}
__device__ __forceinline__ int repof(int i, int H, int eo) {
  return (i <= eo) ? i : H - 1 - 2 * eo + i;
}

__device__ __forceinline__ vbf8 max8(vbf8 a, vbf8 b) {
  us8 ua = __builtin_bit_cast(us8, a), ub = __builtin_bit_cast(us8, b);
  us8 o;
#pragma unroll
  for (int e = 0; e < 8; ++e) o[e] = ua[e] > ub[e] ? ua[e] : ub[e];
  return __builtin_bit_cast(vbf8, o);
}

// ---------------------------------------------------------------------------
// setup: precompute MFMA weight fragments for the pillar net.
// ---------------------------------------------------------------------------
__global__ void setup_kernel(const float* __restrict__ w1, const float* __restrict__ b1,
                             const float* __restrict__ s1, const float* __restrict__ t1,
                             const float* __restrict__ w2, const float* __restrict__ b2,
                             const float* __restrict__ s2, const float* __restrict__ t2,
                             __bf16* __restrict__ wfrag, float* __restrict__ be2f) {
  int l = threadIdx.x;                       // 0..63
  int s = l & 15, g = l >> 4;
#pragma unroll
  for (int m = 0; m < 4; ++m) {
    int c = 32 * (m & 1) + 8 * (s >> 2) + 4 * (m >> 1) + (s & 3);
#pragma unroll
    for (int e = 0; e < 8; ++e) {
      int k = g * 8 + e;
      float v = 0.f;
      if (k < 9)       v = w1[k * 64 + c] * s1[c];
      else if (k == 9) v = fmaf(b1[c], s1[c], t1[c]);
      wfrag[(m * 64 + l) * 8 + e] = (__bf16)v;
    }
    int co = s + 16 * m;
#pragma unroll
    for (int e = 0; e < 8; ++e) {
      int k = g * 8 + e;
      wfrag[((4 + m) * 64 + l) * 8 + e] = (__bf16)(w2[k * 64 + co] * s2[co]);
      wfrag[((8 + m) * 64 + l) * 8 + e] = (__bf16)(w2[(32 + k) * 64 + co] * s2[co]);
    }
    be2f[m * 64 + l] = fmaf(b2[co], s2[co], t2[co]);
  }
}

// ---------------------------------------------------------------------------
// weight transpose+convert, LDS-tiled: HWIO [tap][ci][co] f32 -> [tap][co][ci] bf16
// ---------------------------------------------------------------------------
__global__ __launch_bounds__(256) void convw_kernel(
    const float* __restrict__ k1, const float* __restrict__ k2,
    const float* __restrict__ k3, const float* __restrict__ k4,
    const float* __restrict__ k5, const float* __restrict__ k6,
    const float* __restrict__ kh, __bf16* __restrict__ wT) {
  __shared__ float tile[64][65];
  const int tCI[7]    = {64, 64, 64, 128, 128, 256, 256};
  const int tCO[7]    = {64, 64, 128, 128, 256, 256, 256};
  const int tOFF[7]   = {0, 36864, 73728, 147456, 294912, 589824, 1179648};
  const int tTILES[7] = {9, 9, 18, 36, 72, 144, 144};
  int bid = blockIdx.x;
  int ti = 0, acc = 0;
  while (ti < 6 && bid >= acc + tTILES[ti]) { acc += tTILES[ti]; ++ti; }
  int lt = bid - acc;
  int CI = tCI[ti], CO = tCO[ti];
  const float* src;
  if (ti == 0) src = k1; else if (ti == 1) src = k2; else if (ti == 2) src = k3;
  else if (ti == 3) src = k4; else if (ti == 4) src = k5; else if (ti == 5) src = k6;
  else src = kh;
  int cot = CO / 64, tpt = (CI / 64) * cot;
  int tap = lt / tpt; int r2 = lt - tap * tpt;
  int ci0 = (r2 / cot) * 64, co0 = (r2 % cot) * 64;
  const float* sp = src + (size_t)(tap * CI + ci0) * CO + co0;
  int t = threadIdx.x;
  int lr = t >> 6, lc = t & 63;
#pragma unroll
  for (int rr = 0; rr < 64; rr += 4)
    tile[rr + lr][lc] = sp[(size_t)(rr + lr) * CO + lc];
  __syncthreads();
  __bf16* dst = wT + tOFF[ti] + ((size_t)tap * CO + co0) * CI + ci0;
#pragma unroll
  for (int rr = 0; rr < 64; rr += 4)
    dst[(size_t)(rr + lr) * CI + lc] = (__bf16)tile[lc][rr + lr];
}

// ---------------------------------------------------------------------------
// Stage A: pillar feature net, 1-deep group software pipeline.
// ---------------------------------------------------------------------------
__global__ __launch_bounds__(256) void pillar_kernel(
    const float* __restrict__ pil, const int* __restrict__ npt,
    const __bf16* __restrict__ wfrag, const float* __restrict__ be2f,
    float* __restrict__ partial, int* __restrict__ pcnt)
{
  __shared__ float redf[4][64];
  __shared__ int redc[4];
  const int tid = threadIdx.x;
  const int wv = tid >> 6, lane = tid & 63;
  const int s = lane & 15, g = lane >> 4;
  const int wid = blockIdx.x * 4 + wv;       // 0..23999
  const int b = wid / 6000;
  const int p0 = (wid - b * 6000) * 2;

  vbf8 w1f[4], w2f0[4], w2f1[4];
  float be2[4];
#pragma unroll
  for (int m = 0; m < 4; ++m) {
    w1f[m]  = *(const vbf8*)(wfrag + ((0 + m) * 64 + lane) * 8);
    w2f0[m] = *(const vbf8*)(wfrag + ((4 + m) * 64 + lane) * 8);
    w2f1[m] = *(const vbf8*)(wfrag + ((8 + m) * 64 + lane) * 8);
    be2[m] = be2f[m * 64 + lane];
  }

  float fsum[4] = {0.f, 0.f, 0.f, 0.f};
  int cnt = 0;

  for (int i = 0; i < 2; ++i) {
    int pidx = b * 12000 + p0 + i;
    int np = npt[pidx];
    if (np <= 0) continue;     // wave-uniform
    ++cnt;
    float feat[4][4];
#pragma unroll
    for (int n = 0; n < 4; ++n)
#pragma unroll
      for (int r = 0; r < 4; ++r) feat[n][r] = 0.f;

    int ngrp = (np + 15) >> 4;
    const float* pbase = pil + (size_t)pidx * 900;
    const float* pp0 = pbase + s * 9;
    f32x4u lo = *(const f32x4u*)pp0;
    f32x4u hi = *(const f32x4u*)(pp0 + 4);
    float v8 = pp0[8];
    for (int grp = 0; grp < ngrp; ++grp) {
      int g2 = min(grp + 1, ngrp - 1);
      int ptn = min(g2 * 16 + s, 99);
      const float* ppn = pbase + ptn * 9;
      f32x4u nlo = *(const f32x4u*)ppn;
      f32x4u nhi = *(const f32x4u*)(ppn + 4);
      float nv8 = ppn[8];

      vbf8 b1f;
      b1f[0] = (__bf16)(g == 0 ? lo[0] : (g == 1 ? v8 : 0.f));
      b1f[1] = (__bf16)(g == 0 ? lo[1] : (g == 1 ? 1.0f : 0.f));
      b1f[2] = (__bf16)(g == 0 ? lo[2] : 0.f);
      b1f[3] = (__bf16)(g == 0 ? lo[3] : 0.f);
      b1f[4] = (__bf16)(g == 0 ? hi[0] : 0.f);
      b1f[5] = (__bf16)(g == 0 ? hi[1] : 0.f);
      b1f[6] = (__bf16)(g == 0 ? hi[2] : 0.f);
      b1f[7] = (__bf16)(g == 0 ? hi[3] : 0.f);

      const f32x4 z = {0.f, 0.f, 0.f, 0.f};
      f32x4 d1[4];
#pragma unroll
      for (int m = 0; m < 4; ++m)
        d1[m] = __builtin_amdgcn_mfma_f32_16x16x32_bf16(w1f[m], b1f, z, 0, 0, 0);

      vbf8 a2f0, a2f1;
#pragma unroll
      for (int r = 0; r < 4; ++r) {
        a2f0[r]     = (__bf16)fmaxf(d1[0][r], 0.f);
        a2f1[r]     = (__bf16)fmaxf(d1[1][r], 0.f);
        a2f0[4 + r] = (__bf16)fmaxf(d1[2][r], 0.f);
        a2f1[4 + r] = (__bf16)fmaxf(d1[3][r], 0.f);
      }

      f32x4 d2[4];
#pragma unroll
      for (int n = 0; n < 4; ++n) {
        f32x4 cb = {be2[n], be2[n], be2[n], be2[n]};
        d2[n] = __builtin_amdgcn_mfma_f32_16x16x32_bf16(a2f0, w2f0[n], cb, 0, 0, 0);
        d2[n] = __builtin_amdgcn_mfma_f32_16x16x32_bf16(a2f1, w2f1[n], d2[n], 0, 0, 0);
      }
      if (((grp + 1) << 4) <= np) {
#pragma unroll
        for (int n = 0; n < 4; ++n)
#pragma unroll
          for (int r = 0; r < 4; ++r) feat[n][r] = fmaxf(feat[n][r], d2[n][r]);
      } else {
#pragma unroll
        for (int n = 0; n < 4; ++n)
#pragma unroll
          for (int r = 0; r < 4; ++r) {
            float vv = (grp * 16 + 4 * g + r < np) ? d2[n][r] : 0.f;
            feat[n][r] = fmaxf(feat[n][r], vv);
          }
      }
      lo = nlo; hi = nhi; v8 = nv8;
    }
#pragma unroll
    for (int n = 0; n < 4; ++n) {
      float m = fmaxf(fmaxf(feat[n][0], feat[n][1]), fmaxf(feat[n][2], feat[n][3]));
      m = fmaxf(m, __shfl_xor(m, 16));
      m = fmaxf(m, __shfl_xor(m, 32));
      fsum[n] += m;
    }
  }
  if (g == 0) {
#pragma unroll
    for (int n = 0; n < 4; ++n) redf[wv][s + 16 * n] = fsum[n];
  }
  if (lane == 0) redc[wv] = cnt;
  __syncthreads();
  if (tid < 64) {
    float tot = redf[0][tid] + redf[1][tid] + redf[2][tid] + redf[3][tid];
    partial[blockIdx.x * 64 + tid] = tot;
    if (tid == 0) pcnt[blockIdx.x] = redc[0] + redc[1] + redc[2] + redc[3];
  }
}

// finish mean + emit X0 + zero zbuf page
__global__ void mean_kernel(const float* __restrict__ partial,
                            const int* __restrict__ pcnt,
                            __bf16* __restrict__ x0, __bf16* __restrict__ zbuf) {
  int b = blockIdx.x, t = threadIdx.x;
  if (b == 0) zbuf[t] = (__bf16)0.f;
  int c = t & 63, q = t >> 6;
  float sum = 0.f;
  for (int w = q; w < 1500; w += 4) sum += partial[(b * 1500 + w) * 64 + c];
  int cl = 0;
  for (int w = t; w < 1500; w += 256) cl += pcnt[b * 1500 + w];
  __shared__ float sh[256];
  __shared__ int shc[256];
  sh[t] = sum; shc[t] = cl;
  __syncthreads();
  for (int o = 128; o > 0; o >>= 1) {
    if (t < o) shc[t] += shc[t + o];
    __syncthreads();
  }
  if (t < 64) {
    float tot = sh[t] + sh[t + 64] + sh[t + 128] + sh[t + 192];
    x0[b * 64 + t] = (__bf16)(tot / (float)(shc[0] > 0 ? shc[0] : 1));
  }
}

// ---------------------------------------------------------------------------
// Case-grid conv kernel. If POOL: input is the pre-pool grid at size 2H with
// band EIN; 2x2 max pooling fused into the A-fragment loads.
// wave-task = 32-row m-tile x 16-col n-tile; grid = ceil(MT*NT/4) blocks.
// ---------------------------------------------------------------------------
template <int CI, int CO, int H, int EIN, bool POOL, bool HAS_BN, bool OUT_F32>
__global__ __launch_bounds__(256) void caseconv_kernel(
    const __bf16* __restrict__ xin, const __bf16* __restrict__ wt,
    const float* __restrict__ cb, const float* __restrict__ cs,
    const float* __restrict__ ct, __bf16* __restrict__ yout,
    float* __restrict__ yf32, const __bf16* __restrict__ zbuf)
{
  constexpr int EV   = POOL ? (EIN + 1) / 2 : EIN;   // virtual input band @ H
  constexpr int EOUT = EV + 1;
  constexpr int NBI  = 2 * EIN + 1;                  // physical input grid dim
  constexpr int HX   = POOL ? 2 * H : H;             // physical input size
  constexpr int NBO  = 2 * EOUT + 1;
  constexpr int M    = NBO * NBO * 4;
  constexpr int NT   = CO / 16;
  constexpr int KC   = CI / 32;
  constexpr int MT   = (M + 31) / 32;
  const int wid = blockIdx.x * 4 + (threadIdx.x >> 6);
  if (wid >= MT * NT) return;
  const int lane = threadIdx.x & 63;
  const int s = lane & 15, g = lane >> 4;
  const int nt = wid % NT, mt = wid / NT;

  int reph[2], repw[2], bsel[2];
#pragma unroll
  for (int mf = 0; mf < 2; ++mf) {
    int m = mt * 32 + mf * 16 + s; if (m >= M) m = M - 1;
    bsel[mf] = m & 3; int q = m >> 2;
    int bw = q % NBO, bh = q / NBO;
    reph[mf] = repof(bh, H, EOUT); repw[mf] = repof(bw, H, EOUT);
  }

  f32x4 acc0 = {0.f, 0.f, 0.f, 0.f}, acc1 = {0.f, 0.f, 0.f, 0.f};
#pragma unroll
  for (int tap = 0; tap < 9; ++tap) {
    const int dh = tap / 3, dw = tap % 3;
    const __bf16* wtap = wt + ((size_t)tap * CO + nt * 16) * CI + 8 * g;
    const __bf16* base[2][POOL ? 4 : 1];
#pragma unroll
    for (int mf = 0; mf < 2; ++mf) {
      int vh = reph[mf] + dh - 1, vw = repw[mf] + dw - 1;
      if constexpr (POOL) {
        bool valid = (vh >= 0) && (vh < H) && (vw >= 0) && (vw < H);
        int h0 = 0, h1 = 0, w0 = 0, w1 = 0;
        if (valid) {
          h0 = caseof(2 * vh, HX, EIN); h1 = caseof(2 * vh + 1, HX, EIN);
          w0 = caseof(2 * vw, HX, EIN); w1 = caseof(2 * vw + 1, HX, EIN);
        }
        base[mf][0] = valid ? xin + (size_t)((h0 * NBI + w0) * 4 + bsel[mf]) * CI : zbuf;
        base[mf][1] = valid ? xin + (size_t)((h0 * NBI + w1) * 4 + bsel[mf]) * CI : zbuf;
        base[mf][2] = valid ? xin + (size_t)((h1 * NBI + w0) * 4 + bsel[mf]) * CI : zbuf;
        base[mf][3] = valid ? xin + (size_t)((h1 * NBI + w1) * 4 + bsel[mf]) * CI : zbuf;
      } else {
        int jh = caseof(vh, H, EIN), jw = caseof(vw, H, EIN);
        bool v = (jh >= 0) && (jw >= 0);
        base[mf][0] = v ? xin + (size_t)((jh * NBI + jw) * 4 + bsel[mf]) * CI : zbuf;
      }
    }
#pragma unroll
    for (int ck = 0; ck < KC; ++ck) {
      vbf8 a0, a1;
      if constexpr (POOL) {
        a0 = max8(max8(*(const vbf8*)(base[0][0] + ck * 32 + 8 * g),
                       *(const vbf8*)(base[0][1] + ck * 32 + 8 * g)),
                  max8(*(const vbf8*)(base[0][2] + ck * 32 + 8 * g),
                       *(const vbf8*)(base[0][3] + ck * 32 + 8 * g)));
        a1 = max8(max8(*(const vbf8*)(base[1][0] + ck * 32 + 8 * g),
                       *(const vbf8*)(base[1][1] + ck * 32 + 8 * g)),
                  max8(*(const vbf8*)(base[1][2] + ck * 32 + 8 * g),
                       *(const vbf8*)(base[1][3] + ck * 32 + 8 * g)));
      } else {
        a0 = *(const vbf8*)(base[0][0] + ck * 32 + 8 * g);
        a1 = *(const vbf8*)(base[1][0] + ck * 32 + 8 * g);
      }
      vbf8 bb = *(const vbf8*)(wtap + (size_t)s * CI + ck * 32);
      acc0 = __builtin_amdgcn_mfma_f32_16x16x32_bf16(a0, bb, acc0, 0, 0, 0);
      acc1 = __builtin_amdgcn_mfma_f32_16x16x32_bf16(a1, bb, acc1, 0, 0, 0);
    }
  }

  int co = nt * 16 + s;
  float sc, sh;
  if (HAS_BN) { sc = cs[co]; sh = fmaf(cb[co], sc, ct[co]); }
  else        { sc = 1.f;    sh = cb[co]; }
#pragma unroll
  for (int mf = 0; mf < 2; ++mf) {
    f32x4 acc = mf ? acc1 : acc0;
#pragma unroll
    for (int r = 0; r < 4; ++r) {
      int m = mt * 32 + mf * 16 + 4 * g + r;
      if (m < M) {
        float v = fmaxf(fmaf(acc[r], sc, sh), 0.f);
        if constexpr (OUT_F32) yf32[(size_t)m * CO + co] = v;
        else                   yout[(size_t)m * CO + co] = (__bf16)v;
      }
    }
  }
}

// fused 1x1 head conv + scatter: each output element computes its own 256-dot
__global__ void headscatter_kernel(const float* __restrict__ x,
                                   const float* __restrict__ wk,
                                   const float* __restrict__ bias,
                                   float* __restrict__ out) {
  int idx = blockIdx.x * 256 + threadIdx.x;
  if (idx >= 4 * 10 * 27 * 31) return;
  int c = idx % 31;
  int r = (idx / 31) % 27;
  int ch = (idx / (31 * 27)) % 10;
  int b = idx / (31 * 27 * 10);
  int rr = (r <= 7) ? r : ((r >= 20) ? r - 11 : 7);
  int cc = (c <= 7) ? c : ((c >= 24) ? c - 15 : 7);
  int ph = caseof(rr, 16, 5), pw = caseof(cc, 16, 5);
  const float* xr = x + (size_t)((ph * 11 + pw) * 4 + b) * 256;
  float a0 = 0.f, a1 = 0.f, a2 = 0.f, a3 = 0.f;
#pragma unroll 4
  for (int ci = 0; ci < 256; ci += 4) {
    float4 in4 = *(const float4*)(xr + ci);
    a0 = fmaf(in4.x, wk[(ci + 0) * 10 + ch], a0);
    a1 = fmaf(in4.y, wk[(ci + 1) * 10 + ch], a1);
    a2 = fmaf(in4.z, wk[(ci + 2) * 10 + ch], a2);
    a3 = fmaf(in4.w, wk[(ci + 3) * 10 + ch], a3);
  }
  out[idx] = (a0 + a1) + (a2 + a3) + bias[ch];
}

// ---------------------------------------------------------------------------
extern "C" void kernel_launch(void* const* d_in, const int* in_sizes, int n_in,
                              void* d_out, int out_size, void* d_ws, size_t ws_size,
                              hipStream_t stream) {
  (void)in_sizes; (void)n_in; (void)out_size; (void)ws_size;
  const float* pillars = (const float*)d_in[0];
  const float* w1 = (const float*)d_in[1];
  const float* b1 = (const float*)d_in[2];
  const float* s1 = (const float*)d_in[3];
  const float* t1 = (const float*)d_in[4];
  const float* w2 = (const float*)d_in[5];
  const float* b2 = (const float*)d_in[6];
  const float* s2 = (const float*)d_in[7];
  const float* t2 = (const float*)d_in[8];
  const float* ck[6], *cbv[6], *csv[6], *ctv[6];
  for (int i = 0; i < 6; ++i) {
    ck[i]  = (const float*)d_in[9 + i * 4];
    cbv[i] = (const float*)d_in[10 + i * 4];
    csv[i] = (const float*)d_in[11 + i * 4];
    ctv[i] = (const float*)d_in[12 + i * 4];
  }
  const float* hk1 = (const float*)d_in[33];
  const float* hb1 = (const float*)d_in[34];
  const float* hk2 = (const float*)d_in[35];
  const float* hb2 = (const float*)d_in[36];
  const int* num_points = (const int*)d_in[37];
  float* out = (float*)d_out;

  // ---- ws layout ----
  char* wsb = (char*)d_ws;
  size_t off = 0;
  auto alloc = [&](size_t n) { char* p = wsb + off; off = (off + n + 255) & ~(size_t)255; return p; };
  float*  ppart = (float*)alloc(1536000);
  int*    pcnt  = (int*)alloc(24000);
  __bf16* wfrag = (__bf16*)alloc(12288);
  float*  be2f  = (float*)alloc(1024);
  __bf16* wT    = (__bf16*)alloc(3538944);
  __bf16* zbuf  = (__bf16*)alloc(512);
  __bf16* X0    = (__bf16*)alloc(512);       // 1x1x4x64
  __bf16* X1    = (__bf16*)alloc(4608);      // 3x3x4x64
  __bf16* X2    = (__bf16*)alloc(12800);     // 5x5x4x64
  __bf16* X3    = (__bf16*)alloc(25600);     // 5x5x4x128
  __bf16* X4    = (__bf16*)alloc(50176);     // 7x7x4x128
  __bf16* X5    = (__bf16*)alloc(100352);    // 7x7x4x256
  __bf16* X6    = (__bf16*)alloc(165888);    // 9x9x4x256
  float*  XH    = (float*)alloc(495616);     // 11x11x4x256 f32

  __bf16* wt1 = wT + 0;       __bf16* wt2 = wT + 36864;
  __bf16* wt3 = wT + 73728;   __bf16* wt4 = wT + 147456;
  __bf16* wt5 = wT + 294912;  __bf16* wt6 = wT + 589824;
  __bf16* wth = wT + 1179648;

  setup_kernel<<<1, 64, 0, stream>>>(w1, b1, s1, t1, w2, b2, s2, t2, wfrag, be2f);
  convw_kernel<<<432, 256, 0, stream>>>(ck[0], ck[1], ck[2], ck[3], ck[4], ck[5],
                                        hk1, wT);
  pillar_kernel<<<6000, 256, 0, stream>>>(pillars, num_points, wfrag, be2f,
                                          ppart, pcnt);
  mean_kernel<<<4, 256, 0, stream>>>(ppart, pcnt, X0, zbuf);

  // backbone: separate small launches (HW-ordered; barriers removed)
  caseconv_kernel<64, 64, 64, 0, false, true, false><<<2, 256, 0, stream>>>(
      X0, wt1, cbv[0], csv[0], ctv[0], X1, nullptr, zbuf);
  caseconv_kernel<64, 64, 64, 1, false, true, false><<<4, 256, 0, stream>>>(
      X1, wt2, cbv[1], csv[1], ctv[1], X2, nullptr, zbuf);
  caseconv_kernel<64, 128, 32, 2, true, true, false><<<8, 256, 0, stream>>>(
      X2, wt3, cbv[2], csv[2], ctv[2], X3, nullptr, zbuf);
  caseconv_kernel<128, 128, 32, 2, false, true, false><<<14, 256, 0, stream>>>(
      X3, wt4, cbv[3], csv[3], ctv[3], X4, nullptr, zbuf);
  caseconv_kernel<128, 256, 16, 3, true, true, false><<<28, 256, 0, stream>>>(
      X4, wt5, cbv[4], csv[4], ctv[4], X5, nullptr, zbuf);
  caseconv_kernel<256, 256, 16, 3, false, true, false><<<44, 256, 0, stream>>>(
      X5, wt6, cbv[5], csv[5], ctv[5], X6, nullptr, zbuf);
  caseconv_kernel<256, 256, 16, 4, false, false, true><<<64, 256, 0, stream>>>(
      X6, wth, hb1, nullptr, nullptr, nullptr, XH, zbuf);
  headscatter_kernel<<<131, 256, 0, stream>>>(XH, hk2, hb2, out);
}